// Round 10
// baseline (261.597 us; speedup 1.0000x reference)
//
#include <hip/hip_runtime.h>

#define IS 256
#define NEARV 0.1f
#define FARV 100.0f
#define NTX 16                    // 16x16 tiles of 16x16 px
#define NTILES 256
#define CAP 5120                  // per-tile list capacity >= nf -> overflow impossible
#define CHK 32                    // entries per raster chunk (r5: CHK=16 regresses)
#define CPT ((CAP + CHK - 1) / CHK)   // max chunks per tile = 160
#define MAXITEMS (NTILES * CPT)
#define GBLK 1024                 // 4096 waves; launch_bounds(256,4) => whole grid co-resident
#define GWAVES (GBLK * 4)

// ---------------- single fused kernel (producer-consumer, forward-dependency) ----------------
// r9 post-mortem: every static slot->wave map aliases on powers of two; the
// r3 item list (<=1 chunk/wave) is the only verified balance mechanism. r3's
// remaining cost is structural: 3 dispatches + gaps + a 40us near-idle
// binning envelope. This kernel fuses everything into ONE dispatch:
//   blocks 0..19  : zb init + face transform + two-level binning + ticket;
//                   last block builds the item list (ALL VERBATIM r3, benched
//                   107.8 / absmax 0.0) and release-stores flag = nitems+1.
//   all blocks    : spin on the flag (agent-scope acquire, s_sleep-throttled),
//                   then run the verbatim r3 raster over items.
// Deadlock-safe WITHOUT cooperative launch: (a) flag setters are the lowest
// block IDs -- dispatched first, and they never wait on any other block;
// (b) belt-and-braces: 1024 blocks x 4 waves at <=128 VGPR / 8.5KB LDS are
// fully co-resident on 256 CUs anyway. Memory visibility uses the r1/r3-
// proven chain: writes -> __threadfence -> ticket RMW -> epilogue ->
// __threadfence -> release-store flag; consumers acquire-load the flag.
// count/ticket/flag are cleared by a 1.5KB hipMemsetAsync before the kernel
// (stream-ordered DMA; same pattern as r8, harness-verified).
__launch_bounds__(256, 4)
__global__ void kall(const float* __restrict__ verts, const int* __restrict__ faces,
                     float4* __restrict__ fd, int* __restrict__ count,
                     unsigned short* __restrict__ list, int* __restrict__ misc,
                     int* __restrict__ items, unsigned int* __restrict__ zb, int nf) {
    __shared__ int scnt[NTILES];
    __shared__ int sbase[NTILES];
    __shared__ int slast;
    __shared__ float4 sdata[4][CHK * 3];   // 6 KB: [wave][entry*3 + part]
    const int tid = threadIdx.x;
    const int bid = blockIdx.x;
    const int npb = (nf + 255) / 256;      // 20 binning blocks

    if (bid < npb) {                       // block-uniform: barriers inside are safe
        // ---- zb init by the binning threads (completes before ticket/flag) ----
        {
            uint4* zb4 = (uint4*)zb;
            const uint4 farv = make_uint4(0x42C80000u, 0x42C80000u, 0x42C80000u, 0x42C80000u);
            for (int i = bid * 256 + tid; i < (IS * IS) / 4; i += npb * 256) zb4[i] = farv;
        }
        for (int t = tid; t < NTILES; t += 256) scnt[t] = 0;
        __syncthreads();

        const int f = bid * 256 + tid;
        int kx0 = 0, kx1 = -1, ky0 = 0, ky1 = -1;     // empty range for dead faces
        float bxmin = 0.f, bymin = 0.f, bxmax = -1.f, bymax = -1.f;
        if (f < nf) {
            int i0 = faces[f * 3 + 0];
            int i1 = faces[f * 3 + 1];
            int i2 = faces[f * 3 + 2];
            // transform (v - eye; R == I exactly in fp32 for this camera)
            float z0 = verts[i0 * 3 + 2] + 2.7320508075688772f;
            float z1 = verts[i1 * 3 + 2] + 2.7320508075688772f;
            float z2 = verts[i2 * 3 + 2] + 2.7320508075688772f;
            bool front = (z0 > NEARV) && (z1 > NEARV) && (z2 > NEARV);
            float zs0 = (fabsf(z0) < 1e-5f) ? 1e-5f : z0;
            float zs1 = (fabsf(z1) < 1e-5f) ? 1e-5f : z1;
            float zs2 = (fabsf(z2) < 1e-5f) ? 1e-5f : z2;
            float d0 = zs0 * 0.57735026918962576f;  // zs * tan(30 deg)
            float d1 = zs1 * 0.57735026918962576f;
            float d2 = zs2 * 0.57735026918962576f;
            float x0 = verts[i0 * 3 + 0] / d0;
            float y0 = verts[i0 * 3 + 1] / d0;
            float x1 = verts[i1 * 3 + 0] / d1;
            float y1 = verts[i1 * 3 + 1] / d1;
            float x2 = verts[i2 * 3 + 0] / d2;
            float y2 = verts[i2 * 3 + 1] / d2;
            float area = (x1 - x0) * (y2 - y0) - (x2 - x0) * (y1 - y0);
            if (front && (fabsf(area) > 1e-8f)) {
                bxmin = fminf(x0, fminf(x1, x2));
                bxmax = fmaxf(x0, fmaxf(x1, x2));
                bymin = fminf(y0, fminf(y1, y2));
                bymax = fmaxf(y0, fmaxf(y1, y2));
                float ia = 1.0f / area;  // |area| > 1e-8 so area_s == area
                float iz0 = 1.0f / fmaxf(z0, 1e-4f);
                float iz1 = 1.0f / fmaxf(z1, 1e-4f);
                float iz2 = 1.0f / fmaxf(z2, 1e-4f);
                float4* o = fd + (size_t)f * 4;
                o[0] = make_float4(x0, y0, x1, y1);
                o[1] = make_float4(x2, y2, ia, iz0);
                o[2] = make_float4(iz1, iz2, 0.0f, 0.0f);
                // conservative k-range (+/-1), exact predicate re-tested below
                float tminx = fminf(fmaxf((bxmin * 256.0f + 225.0f) * (1.0f / 32.0f), -2.0f), 17.0f);
                float tmaxx = fminf(fmaxf((bxmax * 256.0f + 255.0f) * (1.0f / 32.0f), -2.0f), 17.0f);
                float tminy = fminf(fmaxf((bymin * 256.0f + 225.0f) * (1.0f / 32.0f), -2.0f), 17.0f);
                float tmaxy = fminf(fmaxf((bymax * 256.0f + 255.0f) * (1.0f / 32.0f), -2.0f), 17.0f);
                kx0 = max(0, (int)ceilf(tminx) - 1);
                kx1 = min(NTX - 1, (int)floorf(tmaxx) + 1);
                ky0 = max(0, (int)ceilf(tminy) - 1);
                ky1 = min(NTX - 1, (int)floorf(tmaxy) + 1);
            }
        }
        // pass A: count (exact dyadic tile-overlap predicate -> bit-identical sets)
        for (int ky = ky0; ky <= ky1; ++ky) {
            float py_lo = (float)(32 * ky - 255) * (1.0f / 256.0f);
            float py_hi = (float)(32 * ky - 225) * (1.0f / 256.0f);
            if (!(bymin <= py_hi && bymax >= py_lo)) continue;
            for (int kx = kx0; kx <= kx1; ++kx) {
                float px_lo = (float)(32 * kx - 255) * (1.0f / 256.0f);
                float px_hi = (float)(32 * kx - 225) * (1.0f / 256.0f);
                if (bxmin <= px_hi && bxmax >= px_lo) atomicAdd(&scnt[ky * NTX + kx], 1);
            }
        }
        __syncthreads();
        for (int t = tid; t < NTILES; t += 256) {
            int c = scnt[t];
            sbase[t] = (c > 0) ? atomicAdd(&count[t], c) : 0;
            scnt[t] = 0;  // reuse as per-block cursor
        }
        __syncthreads();
        // pass B: scatter (order within a tile list irrelevant: min is commutative)
        for (int ky = ky0; ky <= ky1; ++ky) {
            float py_lo = (float)(32 * ky - 255) * (1.0f / 256.0f);
            float py_hi = (float)(32 * ky - 225) * (1.0f / 256.0f);
            if (!(bymin <= py_hi && bymax >= py_lo)) continue;
            for (int kx = kx0; kx <= kx1; ++kx) {
                float px_lo = (float)(32 * kx - 255) * (1.0f / 256.0f);
                float px_hi = (float)(32 * kx - 225) * (1.0f / 256.0f);
                if (bxmin <= px_hi && bxmax >= px_lo) {
                    int t = ky * NTX + kx;
                    int slot = sbase[t] + atomicAdd(&scnt[t], 1);
                    list[(size_t)t * CAP + slot] = (unsigned short)f;
                }
            }
        }
        // ---- ticket; last block builds the item list (verbatim r3) ----
        __threadfence();   // release our zb/fd/list/count writes (all threads)
        __syncthreads();
        if (tid == 0) slast = (atomicAdd(&misc[0], 1) == npb - 1) ? 1 : 0;
        __syncthreads();
        if (slast) {       // block-uniform
            __threadfence();  // acquire: see every block's count[] updates
            int c = __hip_atomic_load(&count[tid], __ATOMIC_RELAXED, __HIP_MEMORY_SCOPE_AGENT);
            int nch = (c + CHK - 1) / CHK;
            scnt[tid] = nch;
            __syncthreads();
            // Hillis-Steele inclusive scan over 256 tiles
            for (int d = 1; d < NTILES; d <<= 1) {
                int v = (tid >= d) ? scnt[tid - d] : 0;
                __syncthreads();
                scnt[tid] += v;
                __syncthreads();
            }
            int off = scnt[tid] - nch;
            for (int k = 0; k < nch; ++k) {
                int n = min(CHK, c - k * CHK);
                items[off + k] = (tid << 16) | (n << 8) | k;   // chunk <= 159 fits 8 bits
            }
            __threadfence();   // release items (all threads)
            __syncthreads();
            if (tid == NTILES - 1)   // flag carries nitems+1 (nonzero when set)
                __hip_atomic_store(&misc[16], scnt[tid] + 1,
                                   __ATOMIC_RELEASE, __HIP_MEMORY_SCOPE_AGENT);
        }
    }

    // ---------------- wait for the flag (all blocks) ----------------
    if (tid == 0) {
        while (__hip_atomic_load(&misc[16], __ATOMIC_ACQUIRE, __HIP_MEMORY_SCOPE_AGENT) == 0) {
            __builtin_amdgcn_s_sleep(32);
            __builtin_amdgcn_s_sleep(32);
        }
    }
    __syncthreads();
    // per-thread acquire load: orders this thread's items/list/fd/zb reads
    const int ni = __hip_atomic_load(&misc[16], __ATOMIC_ACQUIRE, __HIP_MEMORY_SCOPE_AGENT) - 1;

    // ---------------- raster (verbatim r3; <=1 chunk per wave: ni ~2600 < 4096) ----------------
    const int wslot = __builtin_amdgcn_readfirstlane(tid >> 6);
    const int wid = bid * 4 + wslot;
    const int lane = tid & 63;
    const int cx = lane & 15;
    const int ry = lane >> 4;
    float4* sd = &sdata[wslot][0];

    for (int it = wid; it < ni; it += GWAVES) {
        const int pk = __builtin_amdgcn_readfirstlane(items[it]);
        const int tile = pk >> 16;
        const int n = (pk >> 8) & 0xff;
        const int chunk = pk & 0xff;
        const int bx = tile & 15;
        const int by = tile >> 4;
        const int j = bx * 16 + cx;
        const float px = ((float)(2 * j + 1) - 256.0f) * (1.0f / 256.0f);
        float py[4];
        int row[4];
        unsigned int zcur[4];
#pragma unroll
        for (int r = 0; r < 4; ++r) {
            row[r] = by * 16 + ry + 4 * r;
            py[r] = ((float)(2 * row[r] + 1) - 256.0f) * (1.0f / 256.0f);
            zcur[r] = zb[row[r] * IS + j];
        }
        // ---- stage this chunk's face records into wave-private LDS ----
        const unsigned short* lp = list + (size_t)tile * CAP + chunk * CHK;
        if (lane < n) {
            const int fidx = lp[lane];                 // coalesced 2B/lane
            const float4* p = fd + (size_t)fidx * 4;   // 3 dwordx4, batched vmcnt
            float4 b0 = p[0];
            float4 b1 = p[1];
            float4 b2 = p[2];
            sd[lane * 3 + 0] = b0;
            sd[lane * 3 + 1] = b1;
            sd[lane * 3 + 2] = b2;
        }
        // wave-internal write->read ordering (no block barrier: trip counts differ)
        asm volatile("s_waitcnt lgkmcnt(0)" ::: "memory");

        float mx[4] = {0.0f, 0.0f, 0.0f, 0.0f};

#pragma unroll 2
        for (int e = 0; e < n; ++e) {
            float4 a0 = sd[e * 3 + 0];   // uniform addr -> LDS broadcast
            float4 a1 = sd[e * 3 + 1];
            float4 a2 = sd[e * 3 + 2];
            float dx0 = a0.x - px, dx1 = a0.z - px, dx2 = a1.x - px;
#pragma unroll
            for (int r = 0; r < 4; ++r) {
                float dy0 = a0.y - py[r], dy1 = a0.w - py[r], dy2 = a1.y - py[r];
                float e0 = dx1 * dy2 - dx2 * dy1;
                float e1 = dx2 * dy0 - dx0 * dy2;
                float w0 = e0 * a1.z;
                float w1 = e1 * a1.z;
                float w2 = 1.0f - w0 - w1;
                float invz = w0 * a1.w + w1 * a2.x + w2 * a2.y;
                float invzc = fmaxf(invz, 1e-6f);
                // all(w>=0) <=> min3(w0,w1,w2)>=0 (exact; mult by positive ia
                // preserves sign). valid NEAR<zp<FAR <=> 0.01 < invzc < 10.
                float wmin = fminf(fminf(w0, w1), w2);
                bool ok = (wmin >= 0.0f) && (invzc < 10.0f) && (invzc > 0.01f);
                if (ok) mx[r] = fmaxf(mx[r], invzc);
            }
        }
#pragma unroll
        for (int r = 0; r < 4; ++r) {
            if (mx[r] > 0.0f) {
                float zp = 1.0f / mx[r];  // correctly-rounded 1/x monotone => min-exact
                unsigned int zbits = __float_as_uint(zp);
                if (zbits < zcur[r]) atomicMin(&zb[row[r] * IS + j], zbits);
            }
        }
    }
}

extern "C" void kernel_launch(void* const* d_in, const int* in_sizes, int n_in,
                              void* d_out, int out_size, void* d_ws, size_t ws_size,
                              hipStream_t stream) {
    const float* verts = (const float*)d_in[0];
    const int* faces = (const int*)d_in[1];
    unsigned int* zb = (unsigned int*)d_out;  // float bits, min'd in place

    const int nf = in_sizes[1] / 3;  // 5000 (< CAP and < 65536: ushort indices ok)

    char* ws = (char*)d_ws;
    size_t off = 0;
    float4* fd = (float4*)(ws + off);            off += (size_t)nf * 64;          // 320 KB
    off = (off + 255) & ~(size_t)255;
    int* count = (int*)(ws + off);               off += NTILES * 4;               // 1 KB
    int* misc = (int*)(ws + off);                off += 512;  // [0]=ticket, [16]=flag(nitems+1)
    int* items = (int*)(ws + off);               off += (size_t)MAXITEMS * 4;     // 160 KB
    off = (off + 255) & ~(size_t)255;
    unsigned short* list = (unsigned short*)(ws + off);  // 256*5120*2 = 2.62 MB

    // count (1KB) + misc (512B) are contiguous: one stream-ordered DMA clear
    hipMemsetAsync(count, 0, NTILES * 4 + 512, stream);
    kall<<<GBLK, 256, 0, stream>>>(verts, faces, fd, count, list, misc, items, zb, nf);
}

// Round 11
// 136.216 us; speedup vs baseline: 1.9205x; 1.9205x over previous
//
#include <hip/hip_runtime.h>

#define IS 256
#define NEARV 0.1f
#define FARV 100.0f
#define NTX 16                    // 16x16 tiles of 16x16 px
#define NTILES 256
#define CAP 5120                  // per-tile list capacity >= nf -> overflow impossible
#define CHK 32                    // entries per raster chunk (r5: CHK=16 regresses)
#define CPT ((CAP + CHK - 1) / CHK)   // max chunks per tile = 160
#define RBLOCKS 2048
#define RWAVES (RBLOCKS * 4)
#define MAXITEMS (NTILES * CPT)

// ---------------- kernel 1: fused init + prep + TRANSPOSED bin + items ----------------
// The 40us binning envelope (r3/r5/r8/r10) tracked one invariant: face-major
// LDS atomics with SQ_LDS_BANK_CONFLICT = 34334 every round. Huge random
// triangles concentrate on center tiles -> most of a wave's 64 lanes
// atomicAdd the SAME scnt address -> 64-deep same-address serialization on
// the LDS pipe, twice (count + cursor), unhidable by occupancy (r8 proved).
// Fix: TILE-MAJOR binning. The (verbatim) transform stages this block's 256
// face bboxes into LDS; then thread t owns tile t and scans the 256 bboxes
// (same-address LDS reads = broadcast, conflict-free), counting into a
// REGISTER. Zero LDS atomics. One global atomicAdd per (thread,tile)
// (<=20-deep per address) grabs the contiguous range; a rescan scatters.
// Membership = the exact dyadic predicate for ALL tiles -- a superset of the
// old range-clipped sets, safe because the reference tests every face at
// every pixel and the (verbatim) per-pixel math decides coverage.
// zb init folded in (r10-verified); count/misc zeroed by hipMemsetAsync
// (r8-verified). Ticket + Hillis-Steele + item emission verbatim r3.
__launch_bounds__(256)
__global__ void kbinprep(const float* __restrict__ verts, const int* __restrict__ faces,
                         float4* __restrict__ fd, int* __restrict__ count,
                         unsigned short* __restrict__ list, int* __restrict__ misc,
                         int* __restrict__ items, unsigned int* __restrict__ zb, int nf) {
    __shared__ float4 sbb[256];    // per-face bbox (xmin,ymin,xmax,ymax) or sentinel
    __shared__ int scnt[NTILES];
    __shared__ int slast;
    const int tid = threadIdx.x;
    const int bid = blockIdx.x;
    const int nb = gridDim.x;      // 20

    // ---- zb init (256KB of FAR bits, coalesced uint4, grid-strided) ----
    {
        uint4* zb4 = (uint4*)zb;
        const uint4 farv = make_uint4(0x42C80000u, 0x42C80000u, 0x42C80000u, 0x42C80000u);
        for (int i = bid * 256 + tid; i < (IS * IS) / 4; i += nb * 256) zb4[i] = farv;
    }

    // ---- transform + cull (verbatim verified arithmetic); bbox -> LDS ----
    const int f = bid * 256 + tid;
    float4 mybb = make_float4(3.0e8f, 3.0e8f, -3.0e8f, -3.0e8f);  // sentinel: fails all tiles
    if (f < nf) {
        int i0 = faces[f * 3 + 0];
        int i1 = faces[f * 3 + 1];
        int i2 = faces[f * 3 + 2];
        // transform (v - eye; R == I exactly in fp32 for this camera)
        float z0 = verts[i0 * 3 + 2] + 2.7320508075688772f;
        float z1 = verts[i1 * 3 + 2] + 2.7320508075688772f;
        float z2 = verts[i2 * 3 + 2] + 2.7320508075688772f;
        bool front = (z0 > NEARV) && (z1 > NEARV) && (z2 > NEARV);
        float zs0 = (fabsf(z0) < 1e-5f) ? 1e-5f : z0;
        float zs1 = (fabsf(z1) < 1e-5f) ? 1e-5f : z1;
        float zs2 = (fabsf(z2) < 1e-5f) ? 1e-5f : z2;
        float d0 = zs0 * 0.57735026918962576f;  // zs * tan(30 deg)
        float d1 = zs1 * 0.57735026918962576f;
        float d2 = zs2 * 0.57735026918962576f;
        float x0 = verts[i0 * 3 + 0] / d0;
        float y0 = verts[i0 * 3 + 1] / d0;
        float x1 = verts[i1 * 3 + 0] / d1;
        float y1 = verts[i1 * 3 + 1] / d1;
        float x2 = verts[i2 * 3 + 0] / d2;
        float y2 = verts[i2 * 3 + 1] / d2;
        float area = (x1 - x0) * (y2 - y0) - (x2 - x0) * (y1 - y0);
        if (front && (fabsf(area) > 1e-8f)) {
            float bxmin = fminf(x0, fminf(x1, x2));
            float bxmax = fmaxf(x0, fmaxf(x1, x2));
            float bymin = fminf(y0, fminf(y1, y2));
            float bymax = fmaxf(y0, fmaxf(y1, y2));
            float ia = 1.0f / area;  // |area| > 1e-8 so area_s == area
            float iz0 = 1.0f / fmaxf(z0, 1e-4f);
            float iz1 = 1.0f / fmaxf(z1, 1e-4f);
            float iz2 = 1.0f / fmaxf(z2, 1e-4f);
            float4* o = fd + (size_t)f * 4;
            o[0] = make_float4(x0, y0, x1, y1);
            o[1] = make_float4(x2, y2, ia, iz0);
            o[2] = make_float4(iz1, iz2, 0.0f, 0.0f);
            mybb = make_float4(bxmin, bymin, bxmax, bymax);
        }
    }
    sbb[tid] = mybb;
    __syncthreads();

    // ---- tile-major binning: thread tid owns tile tid ----
    // exact dyadic tile bounds (same constants as every verified round)
    const int tkx = tid & 15;
    const int tky = tid >> 4;
    const float px_lo = (float)(32 * tkx - 255) * (1.0f / 256.0f);
    const float px_hi = (float)(32 * tkx - 225) * (1.0f / 256.0f);
    const float py_lo = (float)(32 * tky - 255) * (1.0f / 256.0f);
    const float py_hi = (float)(32 * tky - 225) * (1.0f / 256.0f);

    int cnt = 0;
#pragma unroll 4
    for (int i = 0; i < 256; ++i) {
        float4 bb = sbb[i];   // same addr across lanes -> LDS broadcast, conflict-free
        if (bb.y <= py_hi && bb.w >= py_lo && bb.x <= px_hi && bb.z >= px_lo) ++cnt;
    }
    const int sbase = (cnt > 0) ? atomicAdd(&count[tid], cnt) : 0;  // <=20-deep/address
    const int fbase = bid * 256;
    int k = 0;
#pragma unroll 4
    for (int i = 0; i < 256; ++i) {
        float4 bb = sbb[i];
        if (bb.y <= py_hi && bb.w >= py_lo && bb.x <= px_hi && bb.z >= px_lo) {
            list[(size_t)tid * CAP + sbase + k] = (unsigned short)(fbase + i);
            ++k;
        }
    }

    // ---- last-block epilogue: build item list (verbatim r3) ----
    __syncthreads();
    __threadfence();  // release: our count[] atomicAdds + list writes before the ticket RMW
    if (tid == 0) slast = (atomicAdd(&misc[0], 1) == nb - 1) ? 1 : 0;
    __syncthreads();
    if (!slast) return;
    __threadfence();  // acquire: see every block's count[] updates
    int c = __hip_atomic_load(&count[tid], __ATOMIC_RELAXED, __HIP_MEMORY_SCOPE_AGENT);
    int nch = (c + CHK - 1) / CHK;
    scnt[tid] = nch;
    __syncthreads();
    // Hillis-Steele inclusive scan over 256 tiles
    for (int d = 1; d < NTILES; d <<= 1) {
        int v = (tid >= d) ? scnt[tid - d] : 0;
        __syncthreads();
        scnt[tid] += v;
        __syncthreads();
    }
    int off = scnt[tid] - nch;
    if (tid == NTILES - 1) misc[64] = scnt[tid];  // nitems
    for (int q = 0; q < nch; ++q) {
        int n = min(CHK, c - q * CHK);
        items[off + q] = (tid << 16) | (n << 8) | q;   // chunk <= 159 fits 8 bits
    }
}

// ---------------- kernel 2: raster (verbatim r3 -- benched 107.8, absmax 0.0) ----------------
// One wave per item (ni ~ 2600-5100 < RWAVES -> at most ONE chunk per wave,
// perfect static balance; r4/r7/r9 proved serial multi-chunk waves are the
// failure mode). Batch-staged inner loop: lanes 0..n-1 load one entry index
// (coalesced ushort) + 48B face record (3x dwordx4, ONE vmcnt batch per
// chunk), stage to wave-private LDS, then the entry loop reads via same-
// address ds_read_b128 (broadcast, conflict-free, compiler-pipelined).
// Wave-internal s_waitcnt lgkmcnt(0) orders write->read (no block barrier:
// trip counts differ). Pixel math expression-identical to all verified
// rounds; min3 predicate is an exact reformulation of the three sign tests.
// zb pre-read per pixel; atomicMin only when it would win (zb monotone-
// decreasing -> stale read conservatively safe).
__launch_bounds__(256)
__global__ void kraster(const float4* __restrict__ fd, const unsigned short* __restrict__ list,
                        const int* __restrict__ items, const int* __restrict__ misc,
                        unsigned int* __restrict__ zb) {
    __shared__ float4 sdata[4][CHK * 3];   // 6 KB: [wave][entry*3 + part]
    const int wslot = __builtin_amdgcn_readfirstlane(threadIdx.x >> 6);
    const int wid = blockIdx.x * 4 + wslot;
    const int lane = threadIdx.x & 63;
    const int cx = lane & 15;
    const int ry = lane >> 4;
    const int ni = __builtin_amdgcn_readfirstlane(misc[64]);
    float4* sd = &sdata[wslot][0];

    for (int it = wid; it < ni; it += RWAVES) {
        const int pk = __builtin_amdgcn_readfirstlane(items[it]);
        const int tile = pk >> 16;
        const int n = (pk >> 8) & 0xff;
        const int chunk = pk & 0xff;
        const int bx = tile & 15;
        const int by = tile >> 4;
        const int j = bx * 16 + cx;
        const float px = ((float)(2 * j + 1) - 256.0f) * (1.0f / 256.0f);
        float py[4];
        int row[4];
        unsigned int zcur[4];
#pragma unroll
        for (int r = 0; r < 4; ++r) {
            row[r] = by * 16 + ry + 4 * r;
            py[r] = ((float)(2 * row[r] + 1) - 256.0f) * (1.0f / 256.0f);
            zcur[r] = zb[row[r] * IS + j];
        }
        // ---- stage this chunk's face records into wave-private LDS ----
        const unsigned short* lp = list + (size_t)tile * CAP + chunk * CHK;
        if (lane < n) {
            const int fidx = lp[lane];                 // coalesced 2B/lane
            const float4* p = fd + (size_t)fidx * 4;   // 3 dwordx4, batched vmcnt
            float4 b0 = p[0];
            float4 b1 = p[1];
            float4 b2 = p[2];
            sd[lane * 3 + 0] = b0;
            sd[lane * 3 + 1] = b1;
            sd[lane * 3 + 2] = b2;
        }
        // wave-internal write->read ordering (no block barrier)
        asm volatile("s_waitcnt lgkmcnt(0)" ::: "memory");

        float mx[4] = {0.0f, 0.0f, 0.0f, 0.0f};

#pragma unroll 2
        for (int e = 0; e < n; ++e) {
            float4 a0 = sd[e * 3 + 0];   // uniform addr -> LDS broadcast
            float4 a1 = sd[e * 3 + 1];
            float4 a2 = sd[e * 3 + 2];
            float dx0 = a0.x - px, dx1 = a0.z - px, dx2 = a1.x - px;
#pragma unroll
            for (int r = 0; r < 4; ++r) {
                float dy0 = a0.y - py[r], dy1 = a0.w - py[r], dy2 = a1.y - py[r];
                float e0 = dx1 * dy2 - dx2 * dy1;
                float e1 = dx2 * dy0 - dx0 * dy2;
                float w0 = e0 * a1.z;
                float w1 = e1 * a1.z;
                float w2 = 1.0f - w0 - w1;
                float invz = w0 * a1.w + w1 * a2.x + w2 * a2.y;
                float invzc = fmaxf(invz, 1e-6f);
                // all(w>=0) <=> min3(w0,w1,w2)>=0 (exact; mult by positive ia
                // preserves sign). valid NEAR<zp<FAR <=> 0.01 < invzc < 10.
                float wmin = fminf(fminf(w0, w1), w2);
                bool ok = (wmin >= 0.0f) && (invzc < 10.0f) && (invzc > 0.01f);
                if (ok) mx[r] = fmaxf(mx[r], invzc);
            }
        }
#pragma unroll
        for (int r = 0; r < 4; ++r) {
            if (mx[r] > 0.0f) {
                float zp = 1.0f / mx[r];  // correctly-rounded 1/x monotone => min-exact
                unsigned int zbits = __float_as_uint(zp);
                if (zbits < zcur[r]) atomicMin(&zb[row[r] * IS + j], zbits);
            }
        }
    }
}

extern "C" void kernel_launch(void* const* d_in, const int* in_sizes, int n_in,
                              void* d_out, int out_size, void* d_ws, size_t ws_size,
                              hipStream_t stream) {
    const float* verts = (const float*)d_in[0];
    const int* faces = (const int*)d_in[1];
    unsigned int* zb = (unsigned int*)d_out;  // float bits, min'd in place

    const int nf = in_sizes[1] / 3;  // 5000 (< CAP and < 65536: ushort indices ok)

    char* ws = (char*)d_ws;
    size_t off = 0;
    float4* fd = (float4*)(ws + off);            off += (size_t)nf * 64;          // 320 KB
    off = (off + 255) & ~(size_t)255;
    int* count = (int*)(ws + off);               off += NTILES * 4;               // 1 KB
    int* misc = (int*)(ws + off);                off += 512;  // [0]=ticket, [64]=nitems
    int* items = (int*)(ws + off);               off += (size_t)MAXITEMS * 4;     // 160 KB
    off = (off + 255) & ~(size_t)255;
    unsigned short* list = (unsigned short*)(ws + off);  // 256*5120*2 = 2.62 MB

    const int nb = (nf + 255) / 256;  // 20 blocks

    // count (1KB) + misc (512B) are contiguous: one stream-ordered DMA clear
    hipMemsetAsync(count, 0, NTILES * 4 + 512, stream);
    kbinprep<<<nb, 256, 0, stream>>>(verts, faces, fd, count, list, misc, items, zb, nf);
    kraster<<<RBLOCKS, 256, 0, stream>>>(fd, list, items, misc, zb);
}